// Round 8
// baseline (1411.666 us; speedup 1.0000x reference)
//
#include <hip/hip_runtime.h>

#define NE     800000
#define NWT    50000          // 16-edge wave-tiles
#define GRID   512            // 2 blocks/CU -> 16 waves/CU (4/SIMD)
#define STRIDE (GRID * 8)
#define HP     200            // ushort pitch of H rows (400 B)

typedef __attribute__((ext_vector_type(8))) short short8;   // 8 x bf16
typedef __attribute__((ext_vector_type(4))) float f32x4;

// f32 -> bf16 bits, round-to-nearest-even
__device__ __forceinline__ ushort f2b(float f) {
    unsigned u = __float_as_uint(f);
    return (ushort)((u + 0x7FFFu + ((u >> 16) & 1u)) >> 16);
}

// Pack W1 (192x192) and W2 (192x64) f32 -> bf16 MFMA B-fragments in d_ws.
// Entry e = t*6+k (e<72: W1; e>=72: W2). Lane l supplies
// B[k*32 + (l>>4)*8 + j][t*16 + (l&15)], j=0..7  (16 B per lane).
// (verified: R2/R4/R5/R6/R7 passed with absmax 0.031)
__global__ void pack_w(const float* __restrict__ W1, const float* __restrict__ W2,
                       uint4* __restrict__ wsW)
{
    int i = blockIdx.x * 256 + threadIdx.x;     // 0..6143
    int lane = i & 63, e = i >> 6;
    const float* W; int N, t, k;
    if (e < 72) { W = W1; N = 192; t = e / 6; k = e - t * 6; }
    else        { int e2 = e - 72; W = W2; N = 64; t = e2 / 6; k = e2 - t * 6; }
    const float* p = W + (size_t)(k * 32 + (lane >> 4) * 8) * N + t * 16 + (lane & 15);
    ushort u[8];
    #pragma unroll
    for (int j = 0; j < 8; ++j) u[j] = f2b(p[(size_t)j * N]);
    uint4 d;
    d.x = u[0] | ((unsigned)u[1] << 16);
    d.y = u[2] | ((unsigned)u[3] << 16);
    d.z = u[4] | ((unsigned)u[5] << 16);
    d.w = u[6] | ((unsigned)u[7] << 16);
    wsW[i] = d;
}

// One wave = one 16-edge tile. X gathered straight into A-fragments.
// B-fragments streamed from global (W table is 110 KB -> L2-resident; all
// waves read the same frags -> L1/L2 hits). LDS holds only per-wave H
// buffers (51.2 KB) + consts -> 2 blocks/CU, 4 waves/SIMD for latency hiding.
// No __syncthreads in the main loop.
__global__ __launch_bounds__(512, 4)
void edge_kernel(const float* __restrict__ nf, const float* __restrict__ ef,
                 const int* __restrict__ ei,
                 const float* __restrict__ b1g, const float* __restrict__ gg,
                 const float* __restrict__ btg, const float* __restrict__ b2g,
                 const uint4* __restrict__ wsW, float* __restrict__ out)
{
    __shared__ __align__(16) ushort Hs[8][16 * HP];  // 51200 B: per-wave H buffer
    __shared__ float cs[448];                        // gamma | beta | b2

    const int tid  = threadIdx.x, w = tid >> 6, lane = tid & 63;
    const int lrow = lane & 15, lg = lane >> 4;
    ushort* H = Hs[w];

    if (tid < 448)
        cs[tid] = (tid < 192) ? gg[tid] : (tid < 384) ? btg[tid - 192] : b2g[tid - 384];

    // b1 stays in registers (needed inside the LN sum): 12 VGPR
    float b1v[12];
    #pragma unroll
    for (int t = 0; t < 12; ++t) b1v[t] = b1g[t * 16 + lrow];
    __syncthreads();                 // cs visible; last barrier in the kernel

    for (int wt = blockIdx.x * 8 + w; wt < NWT; wt += STRIDE) {
        const int e0 = wt * 16;

        // ---- gather tile into A-fragments ----
        // lane (lrow,lg) holds X[row=lrow][ks*32 + lg*8 + j], j=0..7
        int iv = 0;
        if (lane < 32) iv = ei[(lane >> 4) * NE + e0 + lrow];
        int ir = __shfl(iv, lrow, 64);
        int ic = __shfl(iv, 16 + lrow, 64);
        const float* pr = nf + (size_t)ir * 64 + lg * 8;
        const float* pc = nf + (size_t)ic * 64 + lg * 8;
        const float* pe = ef + (size_t)(e0 + lrow) * 64 + lg * 8;
        float4 xv[12];
        xv[0]  = *(const float4*)(pr);      xv[1]  = *(const float4*)(pr + 4);
        xv[2]  = *(const float4*)(pr + 32); xv[3]  = *(const float4*)(pr + 36);
        xv[4]  = *(const float4*)(pc);      xv[5]  = *(const float4*)(pc + 4);
        xv[6]  = *(const float4*)(pc + 32); xv[7]  = *(const float4*)(pc + 36);
        xv[8]  = *(const float4*)(pe);      xv[9]  = *(const float4*)(pe + 4);
        xv[10] = *(const float4*)(pe + 32); xv[11] = *(const float4*)(pe + 36);

        short8 xf[6];
        #pragma unroll
        for (int ks = 0; ks < 6; ++ks) {
            float4 a = xv[2 * ks], b = xv[2 * ks + 1];
            xf[ks][0] = (short)f2b(a.x); xf[ks][1] = (short)f2b(a.y);
            xf[ks][2] = (short)f2b(a.z); xf[ks][3] = (short)f2b(a.w);
            xf[ks][4] = (short)f2b(b.x); xf[ks][5] = (short)f2b(b.y);
            xf[ks][6] = (short)f2b(b.z); xf[ks][7] = (short)f2b(b.w);
        }

        // ---- GEMM1: 16x192 = X @ W1, A regs, B streamed from L2 ----
        f32x4 acc1[12];
        #pragma unroll
        for (int t = 0; t < 12; ++t) acc1[t] = (f32x4){0.f, 0.f, 0.f, 0.f};
        #pragma unroll
        for (int ks = 0; ks < 6; ++ks) {
            #pragma unroll
            for (int t = 0; t < 12; ++t) {
                short8 bf = *(const short8*)(wsW + (size_t)(t * 6 + ks) * 64 + lane);
                acc1[t] = __builtin_amdgcn_mfma_f32_16x16x32_bf16(xf[ks], bf, acc1[t], 0, 0, 0);
            }
        }

        // ---- +b1, LayerNorm (16-lane shfl reduce), relu, H -> wave LDS ----
        // D layout: row = lg*4+rr, col = t*16+lrow
        float gvt[12], bvt[12];
        #pragma unroll
        for (int t = 0; t < 12; ++t) {
            gvt[t] = cs[t * 16 + lrow];
            bvt[t] = cs[192 + t * 16 + lrow];
        }
        #pragma unroll
        for (int rr = 0; rr < 4; ++rr) {
            float s = 0.f, q = 0.f;
            #pragma unroll
            for (int t = 0; t < 12; ++t) {
                float v = acc1[t][rr] + b1v[t];
                acc1[t][rr] = v;
                s += v; q += v * v;
            }
            #pragma unroll
            for (int msk = 1; msk < 16; msk <<= 1) {
                s += __shfl_xor(s, msk, 64);
                q += __shfl_xor(q, msk, 64);
            }
            float mean = s * (1.f / 192.f);
            float var  = q * (1.f / 192.f) - mean * mean;
            float rsv  = rsqrtf(var + 1e-5f);
            #pragma unroll
            for (int t = 0; t < 12; ++t) {
                float v = (acc1[t][rr] - mean) * rsv * gvt[t] + bvt[t];
                H[(lg * 4 + rr) * HP + t * 16 + lrow] = f2b(fmaxf(v, 0.f));
            }
        }

        // ---- residual preload (L2-hot: gather touched these rows) ----
        float efv[4][4];
        #pragma unroll
        for (int t = 0; t < 4; ++t)
            #pragma unroll
            for (int rr = 0; rr < 4; ++rr)
                efv[t][rr] = ef[(size_t)(e0 + lg * 4 + rr) * 64 + t * 16 + lrow];

        // ---- GEMM2: 16x64 = H @ W2, A from wave LDS (in-wave dep, no barrier) ----
        f32x4 acc2[4];
        #pragma unroll
        for (int t = 0; t < 4; ++t) acc2[t] = (f32x4){0.f, 0.f, 0.f, 0.f};
        #pragma unroll
        for (int ks = 0; ks < 6; ++ks) {
            short8 hf = *(const short8*)&H[lrow * HP + ks * 32 + lg * 8];
            #pragma unroll
            for (int t = 0; t < 4; ++t) {
                short8 bf = *(const short8*)(wsW + (size_t)(72 + t * 6 + ks) * 64 + lane);
                acc2[t] = __builtin_amdgcn_mfma_f32_16x16x32_bf16(hf, bf, acc2[t], 0, 0, 0);
            }
        }

        // ---- epilogue: + b2 + residual, store ----
        #pragma unroll
        for (int t = 0; t < 4; ++t) {
            float b2v = cs[384 + t * 16 + lrow];
            #pragma unroll
            for (int rr = 0; rr < 4; ++rr) {
                int row = lg * 4 + rr;
                size_t o = (size_t)(e0 + row) * 64 + t * 16 + lrow;
                out[o] = acc2[t][rr] + b2v + efv[t][rr];
            }
        }
    }
}

extern "C" void kernel_launch(void* const* d_in, const int* in_sizes, int n_in,
                              void* d_out, int out_size, void* d_ws, size_t ws_size,
                              hipStream_t stream) {
    const float* nf    = (const float*)d_in[0];
    const float* ef    = (const float*)d_in[1];
    const int*   ei    = (const int*)d_in[2];
    const float* W1    = (const float*)d_in[3];
    const float* b1    = (const float*)d_in[4];
    const float* gamma = (const float*)d_in[5];
    const float* beta  = (const float*)d_in[6];
    const float* W2    = (const float*)d_in[7];
    const float* b2    = (const float*)d_in[8];
    float* out = (float*)d_out;
    uint4* wsW = (uint4*)d_ws;   // 98304 B used

    hipLaunchKernelGGL(pack_w, dim3(24), dim3(256), 0, stream, W1, W2, wsW);
    hipLaunchKernelGGL(edge_kernel, dim3(GRID), dim3(512), 0, stream,
                       nf, ef, ei, b1, gamma, beta, b2, (const uint4*)wsW, out);
}

// Round 9
// 602.148 us; speedup vs baseline: 2.3444x; 2.3444x over previous
//
#include <hip/hip_runtime.h>

#define NE     800000
#define NT     6250          // 128-edge block tiles
#define GRID   512           // 2 blocks/CU target
#define HP     200           // ushort pitch (400 B rows, 16B aligned)

typedef __attribute__((ext_vector_type(8))) short short8;   // 8 x bf16
typedef __attribute__((ext_vector_type(4))) float f32x4;

// f32 -> bf16 bits, round-to-nearest-even
__device__ __forceinline__ ushort f2b(float f) {
    unsigned u = __float_as_uint(f);
    return (ushort)((u + 0x7FFFu + ((u >> 16) & 1u)) >> 16);
}

// Pack W1 (192x192) and W2 (192x64) f32 -> bf16 MFMA B-fragments in d_ws.
// Entry e = t*6+k (e<72: W1; e>=72: W2). Lane l supplies
// B[k*32 + (l>>4)*8 + j][t*16 + (l&15)], j=0..7  (16 B per lane).
// (verified across R2/R4-R8, absmax 0.031)
__global__ void pack_w(const float* __restrict__ W1, const float* __restrict__ W2,
                       uint4* __restrict__ wsW)
{
    int i = blockIdx.x * 256 + threadIdx.x;     // 0..6143
    int lane = i & 63, e = i >> 6;
    const float* W; int N, t, k;
    if (e < 72) { W = W1; N = 192; t = e / 6; k = e - t * 6; }
    else        { int e2 = e - 72; W = W2; N = 64; t = e2 / 6; k = e2 - t * 6; }
    const float* p = W + (size_t)(k * 32 + (lane >> 4) * 8) * N + t * 16 + (lane & 15);
    ushort u[8];
    #pragma unroll
    for (int j = 0; j < 8; ++j) u[j] = f2b(p[(size_t)j * N]);
    uint4 d;
    d.x = u[0] | ((unsigned)u[1] << 16);
    d.y = u[2] | ((unsigned)u[3] << 16);
    d.z = u[4] | ((unsigned)u[5] << 16);
    d.w = u[6] | ((unsigned)u[7] << 16);
    wsW[i] = d;
}

// Block tile = 128 edges. 8 waves = 2 row-groups x 4 col-groups:
// GEMM1: wave owns 64 rows x 48 cols (acc 48 VGPR); GEMM2: 64 rows x 16 cols.
// X staged via LDS (spill-proof); B-fragments streamed from L2 (amortized at
// 128-edge granularity); LDS 58 KB -> 2 blocks/CU, 4 waves/SIMD.
__global__ __launch_bounds__(512, 2)
void edge_kernel(const float* __restrict__ nf, const float* __restrict__ ef,
                 const int* __restrict__ ei,
                 const float* __restrict__ b1g, const float* __restrict__ gg,
                 const float* __restrict__ btg, const float* __restrict__ b2g,
                 const uint4* __restrict__ wsW, float* __restrict__ out)
{
    __shared__ __align__(16) ushort X[128 * HP];   // 51200 B: X, then H in place
    __shared__ float2 sums[128 * 4];               // 4 KB: per (row, cg) partials
    __shared__ float2 musr[128];                   // per-row (mean, rsqrt)
    __shared__ float  cs[448];                     // gamma | beta | b2

    const int tid  = threadIdx.x, w = tid >> 6, lane = tid & 63;
    const int lrow = lane & 15, lg = lane >> 4;
    const int rg   = w >> 2, cg = w & 3;           // 2 row-groups x 4 col-groups
    const int rb   = rg * 64;

    if (tid < 448)
        cs[tid] = (tid < 192) ? gg[tid] : (tid < 384) ? btg[tid - 192] : b2g[tid - 384];

    float b1v[3];
    #pragma unroll
    for (int tl = 0; tl < 3; ++tl) b1v[tl] = b1g[(cg * 3 + tl) * 16 + lrow];

    __syncthreads();

    for (int tile = blockIdx.x; tile < NT; tile += GRID) {
        const int e0 = tile * 128;

        // ---- gather 128x192 f32 -> bf16 into X (2 float4 + 1 b128 write / thr / jj) ----
        #pragma unroll
        for (int jj = 0; jj < 6; ++jj) {
            int fi = jj * 1024 + tid * 2;          // even -> (c4, c4+1) same region
            int le = fi / 48, c4 = fi - le * 48;
            const float* src;
            if (c4 < 16)      src = nf + (size_t)ei[e0 + le] * 64 + c4 * 4;
            else if (c4 < 32) src = nf + (size_t)ei[NE + e0 + le] * 64 + (c4 - 16) * 4;
            else              src = ef + (size_t)(e0 + le) * 64 + (c4 - 32) * 4;
            float4 v0 = *(const float4*)src;
            float4 v1 = *(const float4*)(src + 4);
            uint4 d;
            d.x = f2b(v0.x) | ((unsigned)f2b(v0.y) << 16);
            d.y = f2b(v0.z) | ((unsigned)f2b(v0.w) << 16);
            d.z = f2b(v1.x) | ((unsigned)f2b(v1.y) << 16);
            d.w = f2b(v1.z) | ((unsigned)f2b(v1.w) << 16);
            *(uint4*)&X[le * HP + c4 * 4] = d;
        }
        __syncthreads();                           // A: X ready

        // ---- GEMM1: rows rb..rb+63, cols cg*48..+47; B streamed from L2 ----
        f32x4 acc1[4][3];
        #pragma unroll
        for (int m = 0; m < 4; ++m)
            #pragma unroll
            for (int tl = 0; tl < 3; ++tl)
                acc1[m][tl] = (f32x4){0.f, 0.f, 0.f, 0.f};
        #pragma unroll
        for (int ks = 0; ks < 6; ++ks) {
            short8 a[4];
            #pragma unroll
            for (int m = 0; m < 4; ++m)
                a[m] = *(const short8*)&X[(rb + m * 16 + lrow) * HP + ks * 32 + lg * 8];
            #pragma unroll
            for (int tl = 0; tl < 3; ++tl) {
                short8 bf = *(const short8*)(wsW + (size_t)((cg * 3 + tl) * 6 + ks) * 64 + lane);
                #pragma unroll
                for (int m = 0; m < 4; ++m)
                    acc1[m][tl] = __builtin_amdgcn_mfma_f32_16x16x32_bf16(a[m], bf, acc1[m][tl], 0, 0, 0);
            }
        }

        // ---- LN partials: +b1, 16-lane shfl reduce, (s,q) -> sums[row][cg] ----
        #pragma unroll
        for (int m = 0; m < 4; ++m) {
            #pragma unroll
            for (int rr = 0; rr < 4; ++rr) {
                float s = 0.f, q = 0.f;
                #pragma unroll
                for (int tl = 0; tl < 3; ++tl) {
                    float v = acc1[m][tl][rr] + b1v[tl];
                    acc1[m][tl][rr] = v;
                    s += v; q += v * v;
                }
                #pragma unroll
                for (int msk = 1; msk < 16; msk <<= 1) {
                    s += __shfl_xor(s, msk, 64);
                    q += __shfl_xor(q, msk, 64);
                }
                if (lrow == 0)
                    sums[(rb + m * 16 + lg * 4 + rr) * 4 + cg] = make_float2(s, q);
            }
        }
        __syncthreads();                           // B: partials ready, A1 reads done
        if (tid < 128) {
            float2 a0 = sums[tid * 4 + 0], a1 = sums[tid * 4 + 1];
            float2 a2 = sums[tid * 4 + 2], a3 = sums[tid * 4 + 3];
            float s = a0.x + a1.x + a2.x + a3.x;
            float q = a0.y + a1.y + a2.y + a3.y;
            float mean = s * (1.f / 192.f);
            float var  = q * (1.f / 192.f) - mean * mean;
            musr[tid] = make_float2(mean, rsqrtf(var + 1e-5f));
        }
        __syncthreads();                           // C: musr ready

        // ---- apply LN + relu -> H written into X in place ----
        float gvt[3], bvt[3];
        #pragma unroll
        for (int tl = 0; tl < 3; ++tl) {
            gvt[tl] = cs[(cg * 3 + tl) * 16 + lrow];
            bvt[tl] = cs[192 + (cg * 3 + tl) * 16 + lrow];
        }
        #pragma unroll
        for (int m = 0; m < 4; ++m) {
            #pragma unroll
            for (int rr = 0; rr < 4; ++rr) {
                int row = rb + m * 16 + lg * 4 + rr;
                float2 mr = musr[row];
                #pragma unroll
                for (int tl = 0; tl < 3; ++tl) {
                    float v = (acc1[m][tl][rr] - mr.x) * mr.y * gvt[tl] + bvt[tl];
                    X[row * HP + (cg * 3 + tl) * 16 + lrow] = f2b(fmaxf(v, 0.f));
                }
            }
        }
        __syncthreads();                           // D: H ready

        // ---- GEMM2: rows rb..rb+63, cols cg*16..+15 ----
        f32x4 acc2[4];
        #pragma unroll
        for (int m = 0; m < 4; ++m) acc2[m] = (f32x4){0.f, 0.f, 0.f, 0.f};
        #pragma unroll
        for (int ks = 0; ks < 6; ++ks) {
            short8 bf = *(const short8*)(wsW + (size_t)(72 + cg * 6 + ks) * 64 + lane);
            #pragma unroll
            for (int m = 0; m < 4; ++m) {
                short8 h = *(const short8*)&X[(rb + m * 16 + lrow) * HP + ks * 32 + lg * 8];
                acc2[m] = __builtin_amdgcn_mfma_f32_16x16x32_bf16(h, bf, acc2[m], 0, 0, 0);
            }
        }

        // ---- epilogue: + b2 + f32 edge residual (L2-hot), store ----
        float b2v = cs[384 + cg * 16 + lrow];
        #pragma unroll
        for (int m = 0; m < 4; ++m) {
            #pragma unroll
            for (int rr = 0; rr < 4; ++rr) {
                int row = rb + m * 16 + lg * 4 + rr;
                size_t o = (size_t)(e0 + row) * 64 + cg * 16 + lrow;
                out[o] = acc2[m][rr] + b2v + ef[o];
            }
        }
        __syncthreads();                           // E: safe to overwrite X next tile
    }
}

extern "C" void kernel_launch(void* const* d_in, const int* in_sizes, int n_in,
                              void* d_out, int out_size, void* d_ws, size_t ws_size,
                              hipStream_t stream) {
    const float* nf    = (const float*)d_in[0];
    const float* ef    = (const float*)d_in[1];
    const int*   ei    = (const int*)d_in[2];
    const float* W1    = (const float*)d_in[3];
    const float* b1    = (const float*)d_in[4];
    const float* gamma = (const float*)d_in[5];
    const float* beta  = (const float*)d_in[6];
    const float* W2    = (const float*)d_in[7];
    const float* b2    = (const float*)d_in[8];
    float* out = (float*)d_out;
    uint4* wsW = (uint4*)d_ws;   // 98304 B used

    hipLaunchKernelGGL(pack_w, dim3(24), dim3(256), 0, stream, W1, W2, wsW);
    hipLaunchKernelGGL(edge_kernel, dim3(GRID), dim3(512), 0, stream,
                       nf, ef, ei, b1, gamma, beta, b2, (const uint4*)wsW, out);
}